// Round 1
// baseline (126.855 us; speedup 1.0000x reference)
//
#include <hip/hip_runtime.h>
#include <math.h>

// Problem constants (from reference): B=1024, C=256, H=W=24
static constexpr int B_N  = 1024;
static constexpr int C_N  = 256;
static constexpr int HW_N = 576;           // 24*24, = 144 float4
static constexpr float TEMP_INV = 1.0f / 0.07f;

// ---------------------------------------------------------------------------
// Kernel A: global average pool over H*W. One wave (64 lanes) per (b,c) row.
// Row = 576 contiguous floats = 144 float4. Lanes read consecutive float4
// (fully coalesced, 1KB per instruction), then wave shfl-reduce.
// ---------------------------------------------------------------------------
__global__ __launch_bounds__(256) void pool_kernel(const float* __restrict__ img,
                                                   float* __restrict__ pooled) {
    const int wave = threadIdx.x >> 6;
    const int lane = threadIdx.x & 63;
    const size_t row = (size_t)blockIdx.x * 4 + wave;      // 0 .. 262143
    const float4* src = (const float4*)(img + row * HW_N);

    float s = 0.0f;
    #pragma unroll
    for (int it = 0; it < 3; ++it) {
        int idx = lane + it * 64;                           // 144 f4 per row
        if (idx < 144) {
            float4 v = src[idx];
            s += (v.x + v.y) + (v.z + v.w);
        }
    }
    #pragma unroll
    for (int off = 32; off > 0; off >>= 1) s += __shfl_xor(s, off, 64);
    if (lane == 0) pooled[row] = s * (1.0f / (float)HW_N);
}

// ---------------------------------------------------------------------------
// Kernel B: per-row inverse L2 norms for pooled img rows (r<1024) and text
// rows (r>=1024). One wave per row; 256 floats = exactly one float4/lane.
// Thread (0,0) also zeroes the loss accumulator (runs before kernel C on the
// same stream, so ordering is guaranteed; avoids hipMemset in graph capture).
// ---------------------------------------------------------------------------
__global__ __launch_bounds__(256) void norm_kernel(const float* __restrict__ pooled,
                                                   const float* __restrict__ text,
                                                   float* __restrict__ inv_img,
                                                   float* __restrict__ inv_text,
                                                   float* __restrict__ loss_acc) {
    if (blockIdx.x == 0 && threadIdx.x == 0) *loss_acc = 0.0f;

    const int wave = threadIdx.x >> 6;
    const int lane = threadIdx.x & 63;
    const int r = blockIdx.x * 4 + wave;                    // 0 .. 2047
    const float* srcbase = (r < B_N) ? (pooled + (size_t)r * C_N)
                                     : (text   + (size_t)(r - B_N) * C_N);
    const float4 v = ((const float4*)srcbase)[lane];
    float ss = v.x * v.x + v.y * v.y + v.z * v.z + v.w * v.w;
    #pragma unroll
    for (int off = 32; off > 0; off >>= 1) ss += __shfl_xor(ss, off, 64);
    if (lane == 0) {
        float inv = 1.0f / fmaxf(sqrtf(ss), 1e-12f);        // matches F.normalize
        if (r < B_N) inv_img[r] = inv;
        else         inv_text[r - B_N] = inv;
    }
}

// ---------------------------------------------------------------------------
// Kernel C: fused fp32 GEMM (logits = pooled @ text^T, scaled by inverse
// norms / temperature) + BCE-with-logits loss partial reduction.
// 64x64 tile per 256-thread block, BK=32, 4x4 microtile per thread.
// As: [row][k] padded to 36 floats (16B-aligned float4 rows; a-reads 2-way
// bank alias = free). Bs: transposed [k][col] padded to 68 (b-reads 2-way).
// ---------------------------------------------------------------------------
__global__ __launch_bounds__(256) void gemm_loss_kernel(const float* __restrict__ pooled,
                                                        const float* __restrict__ text,
                                                        const float* __restrict__ inv_img,
                                                        const float* __restrict__ inv_text,
                                                        const int* __restrict__ labels,
                                                        float* __restrict__ loss_acc) {
    __shared__ float As[64][36];
    __shared__ float Bs[32][68];

    const int t  = threadIdx.x;
    const int tx = t & 15;                 // output col group (0..15)
    const int ty = t >> 4;                 // output row group (0..15)
    const int rowBase = (blockIdx.x & 15) * 64;
    const int colBase = (blockIdx.x >> 4) * 64;

    float c[4][4] = {{0.f}};

    for (int kb = 0; kb < C_N; kb += 32) {
        // Stage tiles: 64 rows x 32 k = 512 float4 each, 2 per thread.
        #pragma unroll
        for (int s = 0; s < 2; ++s) {
            const int f4  = t + s * 256;   // 0..511
            const int row = f4 >> 3;       // 0..63
            const int kq  = f4 & 7;        // 0..7 (float4 index along k)
            float4 va = *(const float4*)(pooled + (size_t)(rowBase + row) * C_N + kb + kq * 4);
            *(float4*)&As[row][kq * 4] = va;
            float4 vb = *(const float4*)(text + (size_t)(colBase + row) * C_N + kb + kq * 4);
            Bs[kq * 4 + 0][row] = vb.x;
            Bs[kq * 4 + 1][row] = vb.y;
            Bs[kq * 4 + 2][row] = vb.z;
            Bs[kq * 4 + 3][row] = vb.w;
        }
        __syncthreads();

        #pragma unroll
        for (int k4 = 0; k4 < 8; ++k4) {
            float4 a[4], b[4];
            #pragma unroll
            for (int i = 0; i < 4; ++i) a[i] = *(const float4*)&As[ty * 4 + i][k4 * 4];
            #pragma unroll
            for (int kk = 0; kk < 4; ++kk) b[kk] = *(const float4*)&Bs[k4 * 4 + kk][tx * 4];
            #pragma unroll
            for (int i = 0; i < 4; ++i) {
                const float* ap = (const float*)&a[i];
                #pragma unroll
                for (int kk = 0; kk < 4; ++kk) {
                    const float* bp = (const float*)&b[kk];
                    c[i][0] += ap[kk] * bp[0];
                    c[i][1] += ap[kk] * bp[1];
                    c[i][2] += ap[kk] * bp[2];
                    c[i][3] += ap[kk] * bp[3];
                }
            }
        }
        __syncthreads();
    }

    // Epilogue: scale to logits, BCE-with-logits terms, block partial sum.
    float lsum = 0.0f;
    #pragma unroll
    for (int i = 0; i < 4; ++i) {
        const int gi = rowBase + ty * 4 + i;
        const float si = inv_img[gi] * TEMP_INV;
        const int li = labels[gi];
        #pragma unroll
        for (int j = 0; j < 4; ++j) {
            const int gj = colBase + tx * 4 + j;
            const float x = c[i][j] * si * inv_text[gj];
            const float z = (li == labels[gj]) ? 1.0f : 0.0f;
            // logaddexp(0,x) = softplus(x) = max(x,0) + log1p(exp(-|x|))
            const float sp = fmaxf(x, 0.0f) + log1pf(expf(-fabsf(x)));
            lsum += sp - x * z;
        }
    }

    // Wave reduce then cross-wave via LDS (reuse As; sync first).
    #pragma unroll
    for (int off = 32; off > 0; off >>= 1) lsum += __shfl_xor(lsum, off, 64);
    __syncthreads();
    float* red = &As[0][0];
    if ((t & 63) == 0) red[t >> 6] = lsum;
    __syncthreads();
    if (t == 0) {
        float bsum = red[0] + red[1] + red[2] + red[3];
        atomicAdd(loss_acc, bsum);
    }
}

// ---------------------------------------------------------------------------
// Kernel D: finalize mean.
// ---------------------------------------------------------------------------
__global__ void finalize_kernel(const float* __restrict__ loss_acc,
                                float* __restrict__ out) {
    out[0] = loss_acc[0] * (1.0f / ((float)B_N * (float)B_N));
}

extern "C" void kernel_launch(void* const* d_in, const int* in_sizes, int n_in,
                              void* d_out, int out_size, void* d_ws, size_t ws_size,
                              hipStream_t stream) {
    const float* img    = (const float*)d_in[0];   // [1024,256,24,24] fp32
    const float* text   = (const float*)d_in[1];   // [1024,256] fp32
    const int*   labels = (const int*)d_in[2];     // [1024] int32 (JAX demotes int64)
    float* out = (float*)d_out;

    char* ws = (char*)d_ws;
    float* pooled   = (float*)ws;                          // 1 MiB
    float* inv_img  = (float*)(ws + (1 << 20));            // 4 KiB
    float* inv_text = (float*)(ws + (1 << 20) + 4096);     // 4 KiB
    float* loss_acc = (float*)(ws + (1 << 20) + 8192);     // 4 B

    pool_kernel<<<(B_N * C_N) / 4, 256, 0, stream>>>(img, pooled);
    norm_kernel<<<(2 * B_N) / 4, 256, 0, stream>>>(pooled, text, inv_img, inv_text, loss_acc);
    gemm_loss_kernel<<<256, 256, 0, stream>>>(pooled, text, inv_img, inv_text, labels, loss_acc);
    finalize_kernel<<<1, 1, 0, stream>>>(loss_acc, out);
}

// Round 2
// 118.883 us; speedup vs baseline: 1.0671x; 1.0671x over previous
//
#include <hip/hip_runtime.h>
#include <math.h>

// Problem constants (from reference): B=1024, C=256, H=W=24
static constexpr int B_N  = 1024;
static constexpr int C_N  = 256;
static constexpr int HW_N = 576;           // 24*24, = 144 float4
static constexpr float TEMP_INV = 1.0f / 0.07f;

typedef __attribute__((ext_vector_type(8))) short bf16x8;
typedef __attribute__((ext_vector_type(4))) float f32x4;

// float -> bf16 round-to-nearest-even (inputs are finite; no NaN handling needed)
static __device__ __forceinline__ unsigned short f2bf(float f) {
    unsigned u = __float_as_uint(f);
    return (unsigned short)((u + 0x7FFFu + ((u >> 16) & 1u)) >> 16);
}

// ---------------------------------------------------------------------------
// Kernel A: global average pool over H*W. One wave (64 lanes) per (b,c) row.
// Row = 576 contiguous floats = 144 float4, fully coalesced. Block 0 thread 0
// also zeroes the loss accumulator + ticket (2 launches before they're used).
// ---------------------------------------------------------------------------
__global__ __launch_bounds__(256) void pool_kernel(const float* __restrict__ img,
                                                   float* __restrict__ pooled,
                                                   float* __restrict__ loss_acc,
                                                   unsigned int* __restrict__ ticket) {
    if (blockIdx.x == 0 && threadIdx.x == 0) { *loss_acc = 0.0f; *ticket = 0u; }

    const int wave = threadIdx.x >> 6;
    const int lane = threadIdx.x & 63;
    const size_t row = (size_t)blockIdx.x * 4 + wave;      // 0 .. 262143
    const float4* src = (const float4*)(img + row * HW_N);

    float s = 0.0f;
    #pragma unroll
    for (int it = 0; it < 3; ++it) {
        int idx = lane + it * 64;                           // 144 f4 per row
        if (idx < 144) {
            float4 v = src[idx];
            s += (v.x + v.y) + (v.z + v.w);
        }
    }
    #pragma unroll
    for (int off = 32; off > 0; off >>= 1) s += __shfl_xor(s, off, 64);
    if (lane == 0) pooled[row] = s * (1.0f / (float)HW_N);
}

// ---------------------------------------------------------------------------
// Kernel B: per-row L2-normalize + bf16 cast. One wave per row; rows 0..1023
// are pooled img rows -> Ab, rows 1024..2047 are text rows -> Bb.
// 256 floats/row = exactly one float4 per lane; butterfly reduce gives every
// lane the sum, so all lanes normalize + pack their own 4 values (ushort4, 8B).
// ---------------------------------------------------------------------------
__global__ __launch_bounds__(256) void prep_kernel(const float* __restrict__ pooled,
                                                   const float* __restrict__ text,
                                                   unsigned short* __restrict__ Ab,
                                                   unsigned short* __restrict__ Bb) {
    const int wave = threadIdx.x >> 6;
    const int lane = threadIdx.x & 63;
    const int r = blockIdx.x * 4 + wave;                    // 0 .. 2047
    const float* src = (r < B_N) ? (pooled + (size_t)r * C_N)
                                 : (text   + (size_t)(r - B_N) * C_N);
    const float4 v = ((const float4*)src)[lane];
    float ss = v.x * v.x + v.y * v.y + v.z * v.z + v.w * v.w;
    #pragma unroll
    for (int off = 32; off > 0; off >>= 1) ss += __shfl_xor(ss, off, 64);
    const float inv = 1.0f / fmaxf(sqrtf(ss), 1e-12f);      // matches F.normalize

    ushort4 o;
    o.x = f2bf(v.x * inv); o.y = f2bf(v.y * inv);
    o.z = f2bf(v.z * inv); o.w = f2bf(v.w * inv);
    unsigned short* dst = (r < B_N) ? (Ab + (size_t)r * C_N)
                                    : (Bb + (size_t)(r - B_N) * C_N);
    ((ushort4*)dst)[lane] = o;
}

// ---------------------------------------------------------------------------
// Kernel C: bf16 MFMA GEMM (64x64 tile/block, whole K=256 staged once into
// LDS, XOR-swizzled for conflict-free ds_read_b128 fragment reads) + fused
// BCE-with-logits loss reduction + atomic-ticket finalize (no 4th kernel).
// Rows are pre-normalized, so logits = acc / TEMP directly; the loss is
// transpose-invariant (labels equality is symmetric), making the epilogue
// robust to MFMA operand-layout conventions.
// ---------------------------------------------------------------------------
__global__ __launch_bounds__(256) void gemm_loss_kernel(const unsigned short* __restrict__ Ab,
                                                        const unsigned short* __restrict__ Bb,
                                                        const int* __restrict__ labels,
                                                        float* __restrict__ loss_acc,
                                                        unsigned int* __restrict__ ticket,
                                                        float* __restrict__ out) {
    __shared__ unsigned short Abuf[64 * 256];   // 32 KB, swizzled
    __shared__ unsigned short Bbuf[64 * 256];   // 32 KB, swizzled

    const int t = threadIdx.x;
    const int rowBase = (blockIdx.x & 15) << 6;
    const int colBase = (blockIdx.x >> 4) << 6;

    // ---- Stage both 64x256 bf16 tiles (one shot, no k-loop). 16B chunks:
    // chunk c -> (row = c>>5, kc = c&31); LDS byte = (row*512+kc*16) ^ ((row&7)<<4).
    #pragma unroll
    for (int i = 0; i < 8; ++i) {
        const int c   = t + (i << 8);           // 0..2047
        const int row = c >> 5;
        const int kc  = c & 31;
        const unsigned off = (unsigned)((row << 9) + (kc << 4)) ^ (unsigned)((row & 7) << 4);
        uint4 va = ((const uint4*)(Ab + (size_t)(rowBase + row) * C_N))[kc];
        *(uint4*)((char*)Abuf + off) = va;
        uint4 vb = ((const uint4*)(Bb + (size_t)(colBase + row) * C_N))[kc];
        *(uint4*)((char*)Bbuf + off) = vb;
    }
    __syncthreads();

    // ---- MFMA: wave w owns rows [w*16, w*16+16) x all 64 cols.
    const int w    = t >> 6;
    const int lane = t & 63;
    const int m16  = lane & 15;
    const int kg   = lane >> 4;

    f32x4 acc[4] = {{0.f, 0.f, 0.f, 0.f}, {0.f, 0.f, 0.f, 0.f},
                    {0.f, 0.f, 0.f, 0.f}, {0.f, 0.f, 0.f, 0.f}};

    #pragma unroll
    for (int s = 0; s < 8; ++s) {               // K = 256 = 8 * 32
        const int kc   = (s << 2) + kg;         // 16B chunk index along k
        const int arow = (w << 4) + m16;
        const bf16x8 a = *(const bf16x8*)((char*)Abuf +
                            (((unsigned)((arow << 9) + (kc << 4))) ^ (unsigned)((arow & 7) << 4)));
        #pragma unroll
        for (int ct = 0; ct < 4; ++ct) {
            const int brow = (ct << 4) + m16;
            const bf16x8 b = *(const bf16x8*)((char*)Bbuf +
                                (((unsigned)((brow << 9) + (kc << 4))) ^ (unsigned)((brow & 7) << 4)));
            acc[ct] = __builtin_amdgcn_mfma_f32_16x16x32_bf16(a, b, acc[ct], 0, 0, 0);
        }
    }

    // ---- Epilogue: logits -> BCE terms -> block reduction -> ticket finalize.
    // D frag: col = lane&15, row = (lane>>4)*4 + reg  [measured m89/m91]
    float lsum = 0.0f;
    const int gi0 = rowBase + (w << 4) + (kg << 2);
    int labi[4];
    #pragma unroll
    for (int r = 0; r < 4; ++r) labi[r] = labels[gi0 + r];
    #pragma unroll
    for (int ct = 0; ct < 4; ++ct) {
        const int gj = colBase + (ct << 4) + m16;
        const int labj = labels[gj];
        #pragma unroll
        for (int r = 0; r < 4; ++r) {
            const float x = acc[ct][r] * TEMP_INV;
            const float z = (labi[r] == labj) ? 1.0f : 0.0f;
            const float sp = fmaxf(x, 0.0f) + log1pf(expf(-fabsf(x)));
            lsum += sp - x * z;
        }
    }

    #pragma unroll
    for (int off = 32; off > 0; off >>= 1) lsum += __shfl_xor(lsum, off, 64);
    __syncthreads();                             // done reading LDS; reuse for reduce
    float* red = (float*)Abuf;
    if ((t & 63) == 0) red[w] = lsum;
    __syncthreads();
    if (t == 0) {
        const float bsum = red[0] + red[1] + red[2] + red[3];
        atomicAdd(loss_acc, bsum);
        __threadfence();
        const unsigned old = atomicAdd(ticket, 1u);
        if (old == 255u) {                       // last of 256 blocks
            const float total = atomicAdd(loss_acc, 0.0f);  // device-scope read
            out[0] = total * (1.0f / ((float)B_N * (float)B_N));
        }
    }
}

extern "C" void kernel_launch(void* const* d_in, const int* in_sizes, int n_in,
                              void* d_out, int out_size, void* d_ws, size_t ws_size,
                              hipStream_t stream) {
    const float* img    = (const float*)d_in[0];   // [1024,256,24,24] fp32
    const float* text   = (const float*)d_in[1];   // [1024,256] fp32
    const int*   labels = (const int*)d_in[2];     // [1024] int32 (JAX demotes int64)
    float* out = (float*)d_out;

    char* ws = (char*)d_ws;
    float*          pooled   = (float*)ws;                           // 1 MiB fp32
    unsigned short* Ab       = (unsigned short*)(ws + (1 << 20));    // 512 KiB bf16
    unsigned short* Bb       = (unsigned short*)(ws + (1 << 20) + (512 << 10)); // 512 KiB
    float*          loss_acc = (float*)(ws + (2 << 20));             // 4 B
    unsigned int*   ticket   = (unsigned int*)(ws + (2 << 20) + 4);  // 4 B

    pool_kernel<<<(B_N * C_N) / 4, 256, 0, stream>>>(img, pooled, loss_acc, ticket);
    prep_kernel<<<(2 * B_N) / 4, 256, 0, stream>>>(pooled, text, Ab, Bb);
    gemm_loss_kernel<<<256, 256, 0, stream>>>(Ab, Bb, labels, loss_acc, ticket, out);
}